// Round 14
// baseline (143.647 us; speedup 1.0000x reference)
//
#include <hip/hip_runtime.h>
#include <math.h>

#define BLK 512          // threads per block (8 waves)
#define NBLK 512         // blocks; launch_bounds(512,4) -> >=2 blocks/CU
                         // x 256 CU = 512 -> whole grid co-resident (barrier-safe)
#define GSZ 16           // checkpoints per block in phase B (M/NBLK)
#define SEGW 128         // k-elements per moment segment
#define NSEG_NEAR 6      // segments before s computed exactly (near field)
#define NDEG 8           // expansion degree (moments 0..NDEG)
#define SEGSTRIDE 16     // floats per segment record: d0, M'[0..8], pad

#if __has_builtin(__builtin_amdgcn_rsqf)
#define RSQF(x) __builtin_amdgcn_rsqf(x)
#else
#define RSQF(x) (1.0f / sqrtf(x))
#endif
#if __has_builtin(__builtin_amdgcn_rcpf)
#define RCPF(x) __builtin_amdgcn_rcpf(x)
#else
#define RCPF(x) (1.0f / (x))
#endif

__device__ __forceinline__ float fast_pow(float x, float e) {
  return __expf(e * __logf(x));  // x>0; ~1e-6 rel err vs 0.176 abs budget
}

// ---------------------------------------------------------------------------
// Hand-rolled grid barrier (sense-reversal, device-scope).
// Safe because the ENTIRE grid is co-resident (capacity arithmetic above).
// cnt/gen are zeroed by hipMemsetAsync before every launch (replay-safe).
// threadfence pair makes phase-A global writes visible cross-XCD (G16).
// ---------------------------------------------------------------------------
__device__ __forceinline__ void grid_barrier(unsigned* cnt, unsigned* gen,
                                             unsigned nblk) {
  __syncthreads();
  if (threadIdx.x == 0) {
    __threadfence();  // release: prior global writes visible before arrive
    unsigned g = __hip_atomic_load(gen, __ATOMIC_RELAXED,
                                   __HIP_MEMORY_SCOPE_AGENT);
    unsigned arrived = __hip_atomic_fetch_add(cnt, 1u, __ATOMIC_ACQ_REL,
                                              __HIP_MEMORY_SCOPE_AGENT);
    if (arrived == nblk - 1) {
      __hip_atomic_store(cnt, 0u, __ATOMIC_RELAXED,
                         __HIP_MEMORY_SCOPE_AGENT);
      __hip_atomic_fetch_add(gen, 1u, __ATOMIC_ACQ_REL,
                             __HIP_MEMORY_SCOPE_AGENT);  // orders cnt reset
    } else {
      while (__hip_atomic_load(gen, __ATOMIC_ACQUIRE,
                               __HIP_MEMORY_SCOPE_AGENT) == g)
        __builtin_amdgcn_s_sleep(1);
    }
    __threadfence();  // acquire: other blocks' writes now visible
  }
  __syncthreads();
}

// ---------------------------------------------------------------------------
// Far multipole eval + ONE masked near sweep (R11 math, absmax was 0.0).
// Masks select on the VALUE after rsq/exp (NaN-safe — round-2 rule).
// ---------------------------------------------------------------------------
template <bool USE_RSQ>
__device__ __forceinline__ void body2(
    const float* __restrict__ cpw, const float* __restrict__ dd,
    const float* __restrict__ gapp, const float* __restrict__ segdata,
    const float (&Ss)[GSZ], const int (&lo)[GSZ], const int (&rng)[GSZ],
    float (&acc)[GSZ], int nsegmax, int base, int smaxb, float nb, int tid) {
  if (tid < nsegmax) {  // far: thread tid handles segment tid (nsegmax<=121)
    const float* sd = segdata + tid * SEGSTRIDE;
    float d0 = sd[0];
    float m[NDEG + 1];
#pragma unroll
    for (int n = 0; n <= NDEG; ++n) m[n] = sd[1 + n];
#pragma unroll
    for (int j = 0; j < GSZ; ++j) {
      float s_ = Ss[j] + d0;
      float r = RCPF(s_);
      float tb = USE_RSQ ? RSQF(s_) : fast_pow(s_, nb);
      float h = m[NDEG];
#pragma unroll
      for (int n = NDEG - 1; n >= 0; --n) h = fmaf(h, r, m[n]);
      float contrib = tb * h;
      acc[j] += (tid < (lo[j] >> 7)) ? contrib : 0.0f;
    }
  }
  // near: masked sweep over [base, smaxb] (range < 2048 -> 1 iteration)
  for (int kb = base + tid * 4; kb <= smaxb; kb += BLK * 4) {
    float4 c4 = *(const float4*)(cpw + kb);
    float4 d4 = *(const float4*)(dd + kb);
    float4 g4 = *(const float4*)(gapp + kb);
    const float ce[4] = {c4.x, c4.y, c4.z, c4.w};
    const float de[4] = {d4.x, d4.y, d4.z, d4.w};
    const float ge[4] = {g4.x, g4.y, g4.z, g4.w};
#pragma unroll
    for (int e = 0; e < 4; ++e) {
#pragma unroll
      for (int j = 0; j < GSZ; ++j) {
        float inner = fmaf(ce[e], Ss[j], de[e]);  // may be <=0 if masked
        float p = USE_RSQ ? RSQF(inner) : __expf(nb * __logf(inner));
        unsigned off = (unsigned)(kb + e - lo[j]);
        float pm = (off <= (unsigned)rng[j]) ? p : 0.0f;  // select AFTER p
        acc[j] = fmaf(ge[e], pm, acc[j]);
      }
    }
  }
}

// ---------------------------------------------------------------------------
// Single fused kernel (one graph node):
//  A (blocks 0..127): per-segment precompute + moments; block 128: pad fill.
//  barrier.  B (all): GSZ checkpoints -> hub[m].  barrier.
//  C (block 0): deterministic fixed-order reduce -> out[0].
// ---------------------------------------------------------------------------
__global__ __launch_bounds__(BLK, 4) void fused_kernel(
    const float* __restrict__ S1, const int* __restrict__ step,
    const float* __restrict__ loss, const float* __restrict__ lrs,
    const float* __restrict__ lr_sum, const float* __restrict__ lr_gap,
    const float* __restrict__ L0_p, const float* __restrict__ A_p,
    const float* __restrict__ alpha_p, const float* __restrict__ B_p,
    const float* __restrict__ C_p, const float* __restrict__ beta_p,
    const float* __restrict__ gamma_p,
    float* __restrict__ cpw, float* __restrict__ dd, float* __restrict__ gapp,
    float* __restrict__ segd, float* __restrict__ hub,
    unsigned* __restrict__ bar, float* __restrict__ out, int T, int M) {
  int bid = blockIdx.x, tid = threadIdx.x;
  int lane = tid & 63, wid = tid >> 6;
  __shared__ float sh[BLK / 64];
  __shared__ float wacc[BLK / 64][GSZ];

  float beta = beta_p[0];
  float nb = -beta;

  // ---------------- Phase A ----------------
  if (bid < 128) {
    float d_ = 0.0f, w_ = 0.0f;
    if (tid < SEGW) {
      int k = bid * SEGW + tid;
      if (k == 0) {
        cpw[0] = 0.0f; dd[0] = 1.0f; gapp[0] = 0.0f;
      } else {
        float g = lr_gap[k], L = lr_sum[k - 1];
        float c = C_p[0] * fast_pow(lrs[k], -gamma_p[0]);
        cpw[k] = c; dd[k] = fmaf(-c, L, 1.0f); gapp[k] = g;
        d_ = 1.0f / c - L;
        w_ = g * fast_pow(c, nb);
      }
    }
    float v = d_;
#pragma unroll
    for (int off = 32; off; off >>= 1) v += __shfl_down(v, off, 64);
    if (lane == 0) sh[wid] = v;
    __syncthreads();
    float d0 = (sh[0] + sh[1]) * (1.0f / 128.0f);
    __syncthreads();

    float delta = d_ - d0;
    float p = w_;   // 0 for inactive lanes -> no contribution
    float b = 1.0f;
    for (int n = 0; n <= NDEG; ++n) {
      v = p;
#pragma unroll
      for (int off = 32; off; off >>= 1) v += __shfl_down(v, off, 64);
      if (lane == 0) sh[wid] = v;
      __syncthreads();
      if (tid == 0) segd[bid * SEGSTRIDE + 1 + n] = b * (sh[0] + sh[1]);
      __syncthreads();
      p *= delta;
      b *= (-beta - (float)n) / (float)(n + 1);
    }
    if (tid == 0) segd[bid * SEGSTRIDE] = d0;
  } else if (bid == 128) {
    if (tid < SEGW) {  // pad [T, T+SEGW) so float4 sweeps never read junk
      int k = T + tid;
      cpw[k] = 0.0f; dd[k] = 1.0f; gapp[k] = 0.0f;
    }
  }

  grid_barrier(bar, bar + 1, NBLK);

  // ---------------- Phase B ----------------
  int mbase = bid * GSZ;
  float Ss[GSZ]; int lo[GSZ]; int rng[GSZ]; float acc[GSZ];
  int nsegmax = 0, base = 1 << 30, smaxb = 0;
#pragma unroll
  for (int j = 0; j < GSZ; ++j) {
    Ss[j] = S1[mbase + j];
    int s = step[mbase + j];
    int ks = max(0, (s >> 7) - NSEG_NEAR);
    lo[j] = ks << 7;
    rng[j] = s - lo[j];
    acc[j] = 0.0f;
    nsegmax = max(nsegmax, ks);
    base = min(base, lo[j]);
    smaxb = max(smaxb, s);
  }

  if (beta == 0.5f)
    body2<true>(cpw, dd, gapp, segd, Ss, lo, rng, acc,
                nsegmax, base, smaxb, nb, tid);
  else
    body2<false>(cpw, dd, gapp, segd, Ss, lo, rng, acc,
                 nsegmax, base, smaxb, nb, tid);

#pragma unroll
  for (int j = 0; j < GSZ; ++j) {
    float v = acc[j];
#pragma unroll
    for (int off = 32; off; off >>= 1) v += __shfl_down(v, off, 64);
    if (lane == 0) wacc[wid][j] = v;
  }
  __syncthreads();

  if (tid < GSZ) {
    int j = tid;
    int m = mbase + j;
    float sgp = 0.0f;
#pragma unroll
    for (int w = 0; w < BLK / 64; ++w) sgp += wacc[w][j];
    int s = step[m];
    float Ssum = S1[m];
    float LD = (lrs[0] - lrs[s]) - sgp;   // telescoped gap sum
    float pred = L0_p[0] + A_p[0] * fast_pow(Ssum, -alpha_p[0]) + B_p[0] * LD;
    pred = fmaxf(pred, 1e-10f);
    float r = __logf(loss[m]) - __logf(pred);
    float a = fabsf(r);
    const float dlt = 0.001f;
    hub[m] = (a <= dlt) ? (0.5f * r * r) : (dlt * (a - 0.5f * dlt));
  }

  grid_barrier(bar, bar + 1, NBLK);

  // ---------------- Phase C ----------------
  if (bid == 0) {
    float s = 0.0f;
    for (int i = 0; i < 16; ++i) s += hub[tid + i * BLK];  // M = 16*BLK
#pragma unroll
    for (int off = 32; off; off >>= 1) s += __shfl_down(s, off, 64);
    if (lane == 0) sh[wid] = s;
    __syncthreads();
    if (tid == 0) {
      float t = 0.0f;
#pragma unroll
      for (int i = 0; i < BLK / 64; ++i) t += sh[i];
      out[0] = t;
    }
  }
}

extern "C" void kernel_launch(void* const* d_in, const int* in_sizes, int n_in,
                              void* d_out, int out_size, void* d_ws, size_t ws_size,
                              hipStream_t stream) {
  const float* S1      = (const float*)d_in[0];
  const float* lrs     = (const float*)d_in[1];
  const float* lr_sum  = (const float*)d_in[2];
  const int*   step    = (const int*)  d_in[3];
  const float* lr_gap  = (const float*)d_in[4];
  const float* loss    = (const float*)d_in[5];
  const float* L0_p    = (const float*)d_in[6];
  const float* A_p     = (const float*)d_in[7];
  const float* alpha_p = (const float*)d_in[8];
  const float* B_p     = (const float*)d_in[9];
  const float* C_p     = (const float*)d_in[10];
  const float* beta_p  = (const float*)d_in[11];
  const float* gamma_p = (const float*)d_in[12];

  int M = in_sizes[0];
  int T = in_sizes[1];
  int Tpad = T + SEGW;

  float* cpw  = (float*)d_ws;            // Tpad
  float* dd   = cpw + Tpad;              // Tpad
  float* gapp = dd + Tpad;               // Tpad
  float* segd = gapp + Tpad;             // 128 * SEGSTRIDE
  float* hub  = segd + 128 * SEGSTRIDE;  // M
  unsigned* bar = (unsigned*)(hub + M);  // 2 words: cnt, gen

  hipMemsetAsync(bar, 0, 2 * sizeof(unsigned), stream);  // replay-safe barrier
  fused_kernel<<<NBLK, BLK, 0, stream>>>(
      S1, step, loss, lrs, lr_sum, lr_gap,
      L0_p, A_p, alpha_p, B_p, C_p, beta_p, gamma_p,
      cpw, dd, gapp, segd, hub, bar, (float*)d_out, T, M);
}

// Round 15
// 53.408 us; speedup vs baseline: 2.6896x; 2.6896x over previous
//
#include <hip/hip_runtime.h>
#include <math.h>

#define BLK 512          // threads per block (8 waves)
#define GSZ 16           // checkpoints per block (M/GSZ = 512 blocks)
#define HSZ 8            // checkpoints per half (waves 0-3 / 4-7)
#define NW 8             // waves per block
#define SEGW 128         // k-elements per moment segment
#define NSEG_NEAR 6      // segments before s computed exactly (near field)
#define NDEG 8           // expansion degree (moments 0..NDEG)
#define LSTRIDE 13       // LDS floats per segment record (odd -> conflict-free)
#define MAXSEG 128
#define SCALEF 1.125899906842624e15f   // 2^50 fixed-point scale
#define INV_SCALE (1.0 / 1.125899906842624e15)

#if __has_builtin(__builtin_amdgcn_rsqf)
#define RSQF(x) __builtin_amdgcn_rsqf(x)
#else
#define RSQF(x) (1.0f / sqrtf(x))
#endif
#if __has_builtin(__builtin_amdgcn_rcpf)
#define RCPF(x) __builtin_amdgcn_rcpf(x)
#else
#define RCPF(x) (1.0f / (x))
#endif

__device__ __forceinline__ float fast_pow(float x, float e) {
  return __expf(e * __logf(x));  // x>0; ~1e-6 rel err vs 0.176 abs budget
}

// 64-lane butterfly sum: every lane ends with the full wave sum (fixed order
// -> deterministic).
__device__ __forceinline__ float bsum64(float v) {
#pragma unroll
  for (int m = 1; m < 64; m <<= 1) v += __shfl_xor(v, m, 64);
  return v;
}

// Device globals: zero-initialized at module load; the LAST block resets them
// after use, so every launch (correctness call, each graph replay) starts
// clean. Order-independent int64 sum -> deterministic output.
__device__ long long g_acc;
__device__ unsigned g_cnt;

// ---------------------------------------------------------------------------
// Single kernel, no grid barrier (R14 lesson: agent-scope spin barriers cost
// ~70us each from cross-XCD coherence traffic). Each block is self-sufficient:
//  1) prep: wave-parallel per-segment moments -> LDS (only segments it needs)
//  2) far:  thread htid evaluates segment htid for its half's 8 checkpoints
//  3) near: exact masked sweep, c/dd/g recomputed on the fly (no staging)
//  4) block reduce -> 16 Huber values -> fixed-point int64 atomicAdd;
//     last-arriving block converts to float, writes out[0], resets globals.
// ---------------------------------------------------------------------------
__global__ __launch_bounds__(BLK, 4) void fused_kernel(
    const float* __restrict__ S1, const int* __restrict__ step,
    const float* __restrict__ loss, const float* __restrict__ lrs,
    const float* __restrict__ lr_sum, const float* __restrict__ lr_gap,
    const float* __restrict__ L0_p, const float* __restrict__ A_p,
    const float* __restrict__ alpha_p, const float* __restrict__ B_p,
    const float* __restrict__ C_p, const float* __restrict__ beta_p,
    const float* __restrict__ gamma_p,
    float* __restrict__ out, int T) {
  __shared__ float segm[MAXSEG][LSTRIDE];
  __shared__ float wacc[NW][GSZ];

  int tid = threadIdx.x, bid = blockIdx.x;
  int lane = tid & 63, wid = tid >> 6;
  int jb = (wid >> 2) * HSZ;   // half 0: waves 0-3 (j 0-7); half 1: waves 4-7
  int htid = tid & 255;        // thread index within half

  float beta = beta_p[0], gam = gamma_p[0], C = C_p[0];
  float nb = -beta;
  float gb = gam * beta;
  float Cmb = __expf(nb * __logf(C));  // C^-beta
  bool rsqpath = (beta == 0.5f);

  int mbase = bid * GSZ;

  // ---- block-wide segment count ----
  int nsegmax = 0;
#pragma unroll
  for (int jj = 0; jj < GSZ; ++jj) {
    int s = step[mbase + jj];
    nsegmax = max(nsegmax, max(0, (s >> 7) - NSEG_NEAR));
  }

  // ---- prep: per-wave segment moments (R11 math; k=0 -> dk=wk=0) ----
  for (int seg = wid; seg < nsegmax; seg += NW) {
    float dk[2], wk[2];
#pragma unroll
    for (int e = 0; e < 2; ++e) {
      int k = seg * SEGW + lane * 2 + e;   // < nsegmax*128 <= 15488 < T
      if (k == 0) {
        dk[e] = 0.0f; wk[e] = 0.0f;
      } else {
        float lg = __logf(lrs[k]);
        float c  = C * __expf(-gam * lg);        // C * lrs^-gamma
        dk[e] = RCPF(c) - lr_sum[k - 1];
        wk[e] = lr_gap[k] * Cmb * __expf(gb * lg);  // g * c^-beta
      }
    }
    float d0 = bsum64(dk[0] + dk[1]) * (1.0f / 128.0f);
    float e0 = dk[0] - d0, e1 = dk[1] - d0;
    float p0 = wk[0], p1 = wk[1];
    float b = 1.0f;                        // binom(-beta, n) recurrence
#pragma unroll
    for (int n = 0; n <= NDEG; ++n) {
      float v = bsum64(p0 + p1);
      if (lane == 0) segm[seg][1 + n] = b * v;
      p0 *= e0; p1 *= e1;
      b *= (nb - (float)n) / (float)(n + 1);
    }
    if (lane == 0) segm[seg][0] = d0;
  }
  __syncthreads();

  // ---- per-half checkpoint state (8-wide arrays: no spill, R6 shape) ----
  float Ss[HSZ], acc[HSZ]; int sv[HSZ], ksg[HSZ];
  int base = 1 << 30, smaxb = 0, nsegh = 0;
#pragma unroll
  for (int jj = 0; jj < HSZ; ++jj) {
    int m = mbase + jb + jj;
    Ss[jj] = S1[m];
    int s = step[m];
    sv[jj] = s;
    int kg = max(0, (s >> 7) - NSEG_NEAR);
    ksg[jj] = kg;
    acc[jj] = 0.0f;
    base = min(base, kg << 7);
    smaxb = max(smaxb, s);
    nsegh = max(nsegh, kg);
  }

  // ---- far field: thread htid = segment htid ----
  if (htid < nsegh) {
    float d0 = segm[htid][0];
    float mm[NDEG + 1];
#pragma unroll
    for (int n = 0; n <= NDEG; ++n) mm[n] = segm[htid][1 + n];
#pragma unroll
    for (int jj = 0; jj < HSZ; ++jj) {
      float s_ = Ss[jj] + d0;
      float r = RCPF(s_);
      float tb = rsqpath ? RSQF(s_) : fast_pow(s_, nb);
      float h = mm[NDEG];
#pragma unroll
      for (int n = NDEG - 1; n >= 0; --n) h = fmaf(h, r, mm[n]);
      float contrib = tb * h;
      acc[jj] += (htid < ksg[jj]) ? contrib : 0.0f;  // select AFTER compute
    }
  }

  // ---- near field: exact masked sweep, values computed on the fly ----
  for (int kb = base + htid * 4; kb <= smaxb; kb += 256 * 4) {
#pragma unroll
    for (int e = 0; e < 4; ++e) {
      int k = kb + e;
      int km = min(k, T - 1);   // clamp loads; k>=T always masked out
      int kl = max(km, 1);      // k==0: g=lr_gap[0]=0 kills the term
      float lg = __logf(lrs[kl]);
      float c  = C * __expf(-gam * lg);
      float ddv = fmaf(-c, lr_sum[kl - 1], 1.0f);
      float g = lr_gap[km];
#pragma unroll
      for (int jj = 0; jj < HSZ; ++jj) {
        float inner = fmaf(c, Ss[jj], ddv);  // may be <=0 if masked
        float p = rsqpath ? RSQF(inner) : __expf(nb * __logf(inner));
        unsigned off = (unsigned)(k - (ksg[jj] << 7));
        unsigned rngj = (unsigned)(sv[jj] - (ksg[jj] << 7));
        float pm = (off <= rngj) ? p : 0.0f;  // select AFTER p (NaN-safe)
        acc[jj] = fmaf(g, pm, acc[jj]);
      }
    }
  }

  // ---- block reduce: wave shuffle, then across waves via LDS ----
#pragma unroll
  for (int jj = 0; jj < HSZ; ++jj) {
    float v = acc[jj];
#pragma unroll
    for (int off = 32; off; off >>= 1) v += __shfl_down(v, off, 64);
    if (lane == 0) wacc[wid][jb + jj] = v;
  }
  __syncthreads();

  // ---- epilogue + deterministic fixed-point global sum ----
  long long ll = 0;
  if (tid < GSZ) {
    int j = tid;
    int m = mbase + j;
    int w0 = (j < HSZ) ? 0 : 4;
    float sgp = wacc[w0][j] + wacc[w0 + 1][j] + wacc[w0 + 2][j] + wacc[w0 + 3][j];
    int s = step[m];
    float Ssum = S1[m];
    float LD = (lrs[0] - lrs[s]) - sgp;   // telescoped gap sum
    float pred = L0_p[0] + A_p[0] * fast_pow(Ssum, -alpha_p[0]) + B_p[0] * LD;
    pred = fmaxf(pred, 1e-10f);
    float r = __logf(loss[m]) - __logf(pred);
    float a = fabsf(r);
    const float dlt = 0.001f;
    float hubv = (a <= dlt) ? (0.5f * r * r) : (dlt * (a - 0.5f * dlt));
    ll = (long long)(hubv * SCALEF + 0.5f);  // hubv >= 0
  }
  if (wid == 0) {
#pragma unroll
    for (int off = 8; off; off >>= 1) ll += __shfl_down(ll, off, 64);
    if (lane == 0) {
      __hip_atomic_fetch_add(&g_acc, ll, __ATOMIC_RELAXED,
                             __HIP_MEMORY_SCOPE_AGENT);
      unsigned old = __hip_atomic_fetch_add(&g_cnt, 1u, __ATOMIC_ACQ_REL,
                                            __HIP_MEMORY_SCOPE_AGENT);
      if (old == gridDim.x - 1) {  // last block: all adds visible (acquire)
        long long tot = __hip_atomic_load(&g_acc, __ATOMIC_RELAXED,
                                          __HIP_MEMORY_SCOPE_AGENT);
        out[0] = (float)((double)tot * INV_SCALE);
        __hip_atomic_store(&g_acc, 0ll, __ATOMIC_RELAXED,
                           __HIP_MEMORY_SCOPE_AGENT);   // self-clean for
        __hip_atomic_store(&g_cnt, 0u, __ATOMIC_RELAXED,
                           __HIP_MEMORY_SCOPE_AGENT);   // next launch/replay
      }
    }
  }
}

extern "C" void kernel_launch(void* const* d_in, const int* in_sizes, int n_in,
                              void* d_out, int out_size, void* d_ws, size_t ws_size,
                              hipStream_t stream) {
  const float* S1      = (const float*)d_in[0];
  const float* lrs     = (const float*)d_in[1];
  const float* lr_sum  = (const float*)d_in[2];
  const int*   step    = (const int*)  d_in[3];
  const float* lr_gap  = (const float*)d_in[4];
  const float* loss    = (const float*)d_in[5];
  const float* L0_p    = (const float*)d_in[6];
  const float* A_p     = (const float*)d_in[7];
  const float* alpha_p = (const float*)d_in[8];
  const float* B_p     = (const float*)d_in[9];
  const float* C_p     = (const float*)d_in[10];
  const float* beta_p  = (const float*)d_in[11];
  const float* gamma_p = (const float*)d_in[12];

  int M = in_sizes[0];
  int T = in_sizes[1];

  fused_kernel<<<M / GSZ, BLK, 0, stream>>>(
      S1, step, loss, lrs, lr_sum, lr_gap,
      L0_p, A_p, alpha_p, B_p, C_p, beta_p, gamma_p,
      (float*)d_out, T);
}

// Round 16
// 36.706 us; speedup vs baseline: 3.9135x; 1.4550x over previous
//
#include <hip/hip_runtime.h>
#include <math.h>

#define BLK 1024         // threads per block (16 waves)
#define NBLK 256         // blocks (M/GSZ)
#define GSZ 32           // checkpoints per block
#define HSZ 8            // checkpoints per group (4 waves per group)
#define NW 16            // waves per block
#define SEGW 128         // k-elements per moment segment
#define NSEG_NEAR 6      // segments before s computed exactly (near field)
#define NDEG 8           // expansion degree (moments 0..NDEG)
#define LSTRIDE 13       // LDS floats per segment record (odd -> conflict-free)
#define MAXSEG 128
#define GRPBLK 16        // blocks per atomic group (NBLK/16 groups)
#define SCALEF 1.125899906842624e15f   // 2^50 fixed-point scale
#define INV_SCALE (1.0 / 1.125899906842624e15)

#if __has_builtin(__builtin_amdgcn_rsqf)
#define RSQF(x) __builtin_amdgcn_rsqf(x)
#else
#define RSQF(x) (1.0f / sqrtf(x))
#endif
#if __has_builtin(__builtin_amdgcn_rcpf)
#define RCPF(x) __builtin_amdgcn_rcpf(x)
#else
#define RCPF(x) (1.0f / (x))
#endif

__device__ __forceinline__ float fast_pow(float x, float e) {
  return __expf(e * __logf(x));  // x>0; ~1e-6 rel err vs 0.176 abs budget
}

__device__ __forceinline__ float bsum64(float v) {
#pragma unroll
  for (int m = 1; m < 64; m <<= 1) v += __shfl_xor(v, m, 64);
  return v;
}

// Atomic tree slots: each on its OWN 128B line (R15 lesson: adjacent
// acc/cnt on one line serialized 1024 cross-XCD ops -> ~40us tail).
// Zero-init at load; last users reset -> clean for every replay.
struct __align__(128) Slot { long long acc; unsigned cnt; };
__device__ Slot g_grp[NBLK / GRPBLK];   // 16 group slots
__device__ Slot g_root;

// ---------------------------------------------------------------------------
// Single kernel, no grid barrier, tree-reduced finale.
//  1) prep: wave-parallel per-segment moments -> LDS (replicated per block)
//  2) far:  thread htid evaluates segment htid for its group's 8 checkpoints
//  3) near: exact masked sweep, c/dd/g recomputed on the fly (no staging)
//  4) block partial (fixed-point int64) -> group slot -> root -> out[0]
// ---------------------------------------------------------------------------
__global__ __launch_bounds__(BLK, 2) void fused_kernel(
    const float* __restrict__ S1, const int* __restrict__ step,
    const float* __restrict__ loss, const float* __restrict__ lrs,
    const float* __restrict__ lr_sum, const float* __restrict__ lr_gap,
    const float* __restrict__ L0_p, const float* __restrict__ A_p,
    const float* __restrict__ alpha_p, const float* __restrict__ B_p,
    const float* __restrict__ C_p, const float* __restrict__ beta_p,
    const float* __restrict__ gamma_p,
    float* __restrict__ out, int T) {
  __shared__ float segm[MAXSEG][LSTRIDE];
  __shared__ float wacc[NW][GSZ];

  int tid = threadIdx.x, bid = blockIdx.x;
  int lane = tid & 63, wid = tid >> 6;
  int grp = tid >> 8;          // 4 waves per group
  int jb = grp * HSZ;
  int htid = tid & 255;        // thread index within group

  float beta = beta_p[0], gam = gamma_p[0], C = C_p[0];
  float nb = -beta;
  float gb = gam * beta;
  float Cmb = __expf(nb * __logf(C));  // C^-beta
  bool rsqpath = (beta == 0.5f);

  int mbase = bid * GSZ;

  // ---- block-wide segment count ----
  int nsegmax = 0;
#pragma unroll
  for (int jj = 0; jj < GSZ; ++jj) {
    int s = step[mbase + jj];
    nsegmax = max(nsegmax, max(0, (s >> 7) - NSEG_NEAR));
  }

  // ---- prep: per-wave segment moments (k=0 -> dk=wk=0) ----
  for (int seg = wid; seg < nsegmax; seg += NW) {
    float dk[2], wk[2];
#pragma unroll
    for (int e = 0; e < 2; ++e) {
      int k = seg * SEGW + lane * 2 + e;   // < 121*128 < T
      if (k == 0) {
        dk[e] = 0.0f; wk[e] = 0.0f;
      } else {
        float lg = __logf(lrs[k]);
        float c  = C * __expf(-gam * lg);           // C * lrs^-gamma
        dk[e] = RCPF(c) - lr_sum[k - 1];
        wk[e] = lr_gap[k] * Cmb * __expf(gb * lg);  // g * c^-beta
      }
    }
    float d0 = bsum64(dk[0] + dk[1]) * (1.0f / 128.0f);
    float e0 = dk[0] - d0, e1 = dk[1] - d0;
    float p0 = wk[0], p1 = wk[1];
    float b = 1.0f;                        // binom(-beta, n) recurrence
#pragma unroll
    for (int n = 0; n <= NDEG; ++n) {
      float v = bsum64(p0 + p1);
      if (lane == 0) segm[seg][1 + n] = b * v;
      p0 *= e0; p1 *= e1;
      b *= (nb - (float)n) / (float)(n + 1);
    }
    if (lane == 0) segm[seg][0] = d0;
  }
  __syncthreads();

  // ---- per-group checkpoint state (8-wide arrays: no spill) ----
  float Ss[HSZ], acc[HSZ]; int sv[HSZ], ksg[HSZ];
  int base = 1 << 30, smaxb = 0, nsegh = 0;
#pragma unroll
  for (int jj = 0; jj < HSZ; ++jj) {
    int m = mbase + jb + jj;
    Ss[jj] = S1[m];
    int s = step[m];
    sv[jj] = s;
    int kg = max(0, (s >> 7) - NSEG_NEAR);
    ksg[jj] = kg;
    acc[jj] = 0.0f;
    base = min(base, kg << 7);
    smaxb = max(smaxb, s);
    nsegh = max(nsegh, kg);
  }

  // ---- far field: thread htid = segment htid ----
  if (htid < nsegh) {
    float d0 = segm[htid][0];
    float mm[NDEG + 1];
#pragma unroll
    for (int n = 0; n <= NDEG; ++n) mm[n] = segm[htid][1 + n];
#pragma unroll
    for (int jj = 0; jj < HSZ; ++jj) {
      float s_ = Ss[jj] + d0;
      float r = RCPF(s_);
      float tb = rsqpath ? RSQF(s_) : fast_pow(s_, nb);
      float h = mm[NDEG];
#pragma unroll
      for (int n = NDEG - 1; n >= 0; --n) h = fmaf(h, r, mm[n]);
      float contrib = tb * h;
      acc[jj] += (htid < ksg[jj]) ? contrib : 0.0f;  // select AFTER compute
    }
  }

  // ---- near field: exact masked sweep, values computed on the fly ----
  for (int kb = base + htid * 4; kb <= smaxb; kb += 256 * 4) {
#pragma unroll
    for (int e = 0; e < 4; ++e) {
      int k = kb + e;
      int km = min(k, T - 1);   // clamp loads; k>=T always masked out
      int kl = max(km, 1);      // k==0: g=lr_gap[0]=0 kills the term
      float lg = __logf(lrs[kl]);
      float c  = C * __expf(-gam * lg);
      float ddv = fmaf(-c, lr_sum[kl - 1], 1.0f);
      float g = lr_gap[km];
#pragma unroll
      for (int jj = 0; jj < HSZ; ++jj) {
        float inner = fmaf(c, Ss[jj], ddv);  // may be <=0 if masked
        float p = rsqpath ? RSQF(inner) : __expf(nb * __logf(inner));
        unsigned off = (unsigned)(k - (ksg[jj] << 7));
        unsigned rngj = (unsigned)(sv[jj] - (ksg[jj] << 7));
        float pm = (off <= rngj) ? p : 0.0f;  // select AFTER p (NaN-safe)
        acc[jj] = fmaf(g, pm, acc[jj]);
      }
    }
  }

  // ---- block reduce: wave shuffle, then across waves via LDS ----
#pragma unroll
  for (int jj = 0; jj < HSZ; ++jj) {
    float v = acc[jj];
#pragma unroll
    for (int off = 32; off; off >>= 1) v += __shfl_down(v, off, 64);
    if (lane == 0) wacc[wid][jb + jj] = v;
  }
  __syncthreads();

  // ---- epilogue (wave 0, lanes 0..31) + tree-reduced global sum ----
  long long ll = 0;
  if (tid < GSZ) {
    int j = tid;
    int m = mbase + j;
    int w0 = (j >> 3) * 4;
    float sgp = wacc[w0][j] + wacc[w0 + 1][j] + wacc[w0 + 2][j] + wacc[w0 + 3][j];
    int s = step[m];
    float Ssum = S1[m];
    float LD = (lrs[0] - lrs[s]) - sgp;   // telescoped gap sum
    float pred = L0_p[0] + A_p[0] * fast_pow(Ssum, -alpha_p[0]) + B_p[0] * LD;
    pred = fmaxf(pred, 1e-10f);
    float r = __logf(loss[m]) - __logf(pred);
    float a = fabsf(r);
    const float dlt = 0.001f;
    float hubv = (a <= dlt) ? (0.5f * r * r) : (dlt * (a - 0.5f * dlt));
    ll = (long long)(hubv * SCALEF + 0.5f);  // hubv >= 0
  }
  if (wid == 0) {
#pragma unroll
    for (int off = 16; off; off >>= 1) ll += __shfl_down(ll, off, 64);
    if (lane == 0) {
      int gi = bid / GRPBLK;
      __hip_atomic_fetch_add(&g_grp[gi].acc, ll, __ATOMIC_RELAXED,
                             __HIP_MEMORY_SCOPE_AGENT);
      unsigned old = __hip_atomic_fetch_add(&g_grp[gi].cnt, 1u,
                                            __ATOMIC_ACQ_REL,
                                            __HIP_MEMORY_SCOPE_AGENT);
      if (old == GRPBLK - 1) {  // group-last: all 16 adds visible
        long long gsum = __hip_atomic_load(&g_grp[gi].acc, __ATOMIC_RELAXED,
                                           __HIP_MEMORY_SCOPE_AGENT);
        __hip_atomic_store(&g_grp[gi].acc, 0ll, __ATOMIC_RELAXED,
                           __HIP_MEMORY_SCOPE_AGENT);   // self-clean
        __hip_atomic_store(&g_grp[gi].cnt, 0u, __ATOMIC_RELAXED,
                           __HIP_MEMORY_SCOPE_AGENT);
        __hip_atomic_fetch_add(&g_root.acc, gsum, __ATOMIC_RELAXED,
                               __HIP_MEMORY_SCOPE_AGENT);
        unsigned old2 = __hip_atomic_fetch_add(&g_root.cnt, 1u,
                                               __ATOMIC_ACQ_REL,
                                               __HIP_MEMORY_SCOPE_AGENT);
        if (old2 == (NBLK / GRPBLK) - 1) {  // root-last
          long long tot = __hip_atomic_load(&g_root.acc, __ATOMIC_RELAXED,
                                            __HIP_MEMORY_SCOPE_AGENT);
          out[0] = (float)((double)tot * INV_SCALE);
          __hip_atomic_store(&g_root.acc, 0ll, __ATOMIC_RELAXED,
                             __HIP_MEMORY_SCOPE_AGENT);
          __hip_atomic_store(&g_root.cnt, 0u, __ATOMIC_RELAXED,
                             __HIP_MEMORY_SCOPE_AGENT);
        }
      }
    }
  }
}

extern "C" void kernel_launch(void* const* d_in, const int* in_sizes, int n_in,
                              void* d_out, int out_size, void* d_ws, size_t ws_size,
                              hipStream_t stream) {
  const float* S1      = (const float*)d_in[0];
  const float* lrs     = (const float*)d_in[1];
  const float* lr_sum  = (const float*)d_in[2];
  const int*   step    = (const int*)  d_in[3];
  const float* lr_gap  = (const float*)d_in[4];
  const float* loss    = (const float*)d_in[5];
  const float* L0_p    = (const float*)d_in[6];
  const float* A_p     = (const float*)d_in[7];
  const float* alpha_p = (const float*)d_in[8];
  const float* B_p     = (const float*)d_in[9];
  const float* C_p     = (const float*)d_in[10];
  const float* beta_p  = (const float*)d_in[11];
  const float* gamma_p = (const float*)d_in[12];

  int M = in_sizes[0];
  int T = in_sizes[1];

  fused_kernel<<<M / GSZ, BLK, 0, stream>>>(
      S1, step, loss, lrs, lr_sum, lr_gap,
      L0_p, A_p, alpha_p, B_p, C_p, beta_p, gamma_p,
      (float*)d_out, T);
}

// Round 17
// 24.809 us; speedup vs baseline: 5.7902x; 1.4795x over previous
//
#include <hip/hip_runtime.h>
#include <math.h>

#define BLK 1024         // threads per block (16 waves)
#define NBLK 256         // blocks = M/GSZ (1 per CU)
#define GSZ 32           // checkpoints per block
#define HSZ 8            // checkpoints per group (4 waves per group)
#define NW 16            // waves per block
#define SEGW 256         // k-elements per moment segment
#define SEGSH 8          // log2(SEGW)
#define NSEG_NEAR 3      // far/near boundary: 3*256 = 768 steps exact
#define NDEG 6           // expansion degree (moments 0..6); u~0.23 -> 3e-5 rel
#define LSTRIDE 9        // LDS floats per segment record (odd: conflict-free)
#define MAXSEG 64        // 16384/256
#define LSTG 2048        // staged near-field elements (union range + slack)
#define GRPBLK 16        // blocks per atomic group
#define SCALEF 1.125899906842624e15f   // 2^50 fixed-point scale
#define INV_SCALE (1.0 / 1.125899906842624e15)

#if __has_builtin(__builtin_amdgcn_rsqf)
#define RSQF(x) __builtin_amdgcn_rsqf(x)
#else
#define RSQF(x) (1.0f / sqrtf(x))
#endif
#if __has_builtin(__builtin_amdgcn_rcpf)
#define RCPF(x) __builtin_amdgcn_rcpf(x)
#else
#define RCPF(x) (1.0f / (x))
#endif

__device__ __forceinline__ float fast_pow(float x, float e) {
  return __expf(e * __logf(x));  // x>0; ~1e-6 rel err vs 0.176 abs budget
}

__device__ __forceinline__ float bsum64(float v) {
#pragma unroll
  for (int m = 1; m < 64; m <<= 1) v += __shfl_xor(v, m, 64);
  return v;
}

// Atomic tree slots, each on its OWN 128B line (R15/R16 lesson).
// Zero-init at load; last users reset -> clean for every replay.
struct __align__(128) Slot { long long acc; unsigned cnt; };
__device__ Slot g_grp[NBLK / GRPBLK];
__device__ Slot g_root;

// ---------------------------------------------------------------------------
// Whole computation for one block, templated on the beta==0.5 fast path
// (R15/R16 regression suspect: runtime ternary in inner loops made the
// compiler evaluate/branch both transcendental chains per element).
// ---------------------------------------------------------------------------
template <bool USE_RSQ>
__device__ __forceinline__ void body(
    const float* __restrict__ S1, const int* __restrict__ step,
    const float* __restrict__ loss, const float* __restrict__ lrs,
    const float* __restrict__ lr_sum, const float* __restrict__ lr_gap,
    const float* __restrict__ L0_p, const float* __restrict__ A_p,
    const float* __restrict__ alpha_p, const float* __restrict__ B_p,
    float C, float nb, float* __restrict__ out, int T,
    float (&segm)[MAXSEG][LSTRIDE], float (&lc)[LSTG], float (&ldd)[LSTG],
    float (&lgp)[LSTG], float (&wacc)[NW][GSZ], float gam) {
  int tid = threadIdx.x, bid = blockIdx.x;
  int lane = tid & 63, wid = tid >> 6;
  int grp = tid >> 8;          // 4 waves per group of HSZ checkpoints
  int jb = grp * HSZ;
  int htid = tid & 255;

  int mbase = bid * GSZ;

  // ---- block-wide scan (broadcast loads) ----
  int nsegmax = 0, minlo = 1 << 30, utop = 0;
#pragma unroll
  for (int jj = 0; jj < GSZ; ++jj) {
    int s = step[mbase + jj];
    int ks = max(0, (s >> SEGSH) - NSEG_NEAR);
    nsegmax = max(nsegmax, ks);
    minlo = min(minlo, ks << SEGSH);
    utop = max(utop, s);
  }
  int ubase = minlo;
  int ucnt = min(LSTG, (utop - ubase + 7) & ~3);  // >= utop-ubase+4

  // ---- prep: per-wave segment moments (4 k's per lane, unrolled ILP) ----
  for (int seg = wid; seg < nsegmax; seg += NW) {
    float dk[4], wk[4];
#pragma unroll
    for (int e = 0; e < 4; ++e) {
      int k = seg * SEGW + lane * 4 + e;   // < 61*256 < T always
      if (k == 0) {
        dk[e] = 0.0f; wk[e] = 0.0f;        // k=0 contributes nothing
      } else {
        float lg = __logf(lrs[k]);
        float c  = C * __expf(-gam * lg);  // C * lrs^-gamma
        dk[e] = RCPF(c) - lr_sum[k - 1];
        wk[e] = USE_RSQ ? (lr_gap[k] * RSQF(c))
                        : (lr_gap[k] * fast_pow(c, nb));
      }
    }
    float d0 = bsum64(dk[0] + dk[1] + dk[2] + dk[3]) * (1.0f / 256.0f);
    float e0 = dk[0] - d0, e1 = dk[1] - d0, e2 = dk[2] - d0, e3 = dk[3] - d0;
    float p0 = wk[0], p1 = wk[1], p2 = wk[2], p3 = wk[3];
    float b = 1.0f;                        // binom(nb, n) recurrence
#pragma unroll
    for (int n = 0; n <= NDEG; ++n) {      // unrolled: 7 bsum chains overlap
      float v = bsum64(p0 + p1 + p2 + p3);
      if (lane == 0) segm[seg][1 + n] = b * v;
      p0 *= e0; p1 *= e1; p2 *= e2; p3 *= e3;
      b *= (nb - (float)n) / (float)(n + 1);
    }
    if (lane == 0) segm[seg][0] = d0;
  }

  // ---- stage near-field (c, dd, g) once per block into LDS ----
  for (int i = tid; i < ucnt; i += BLK) {
    int k = ubase + i;
    if (k == 0 || k >= T) {
      lc[i] = 0.0f; ldd[i] = 1.0f; lgp[i] = 0.0f;
    } else {
      float lg = __logf(lrs[k]);
      float c  = C * __expf(-gam * lg);
      lc[i] = c;
      ldd[i] = fmaf(-c, lr_sum[k - 1], 1.0f);
      lgp[i] = lr_gap[k];
    }
  }
  __syncthreads();

  // ---- per-group checkpoint state (8-wide arrays: no spill) ----
  float Ss[HSZ], acc[HSZ]; int sv[HSZ], ksg[HSZ];
  int lo_g = 1 << 30, smax_g = 0, nsegh = 0;
#pragma unroll
  for (int jj = 0; jj < HSZ; ++jj) {
    int m = mbase + jb + jj;
    Ss[jj] = S1[m];
    int s = step[m];
    sv[jj] = s;
    int kg = max(0, (s >> SEGSH) - NSEG_NEAR);
    ksg[jj] = kg;
    acc[jj] = 0.0f;
    lo_g = min(lo_g, kg << SEGSH);
    smax_g = max(smax_g, s);
    nsegh = max(nsegh, kg);
  }

  // ---- far field: thread htid evaluates segment htid ----
  if (htid < nsegh) {
    float d0 = segm[htid][0];
    float mm[NDEG + 1];
#pragma unroll
    for (int n = 0; n <= NDEG; ++n) mm[n] = segm[htid][1 + n];
#pragma unroll
    for (int jj = 0; jj < HSZ; ++jj) {
      float s_ = Ss[jj] + d0;
      float r = RCPF(s_);
      float tb = USE_RSQ ? RSQF(s_) : fast_pow(s_, nb);
      float h = mm[NDEG];
#pragma unroll
      for (int n = NDEG - 1; n >= 0; --n) h = fmaf(h, r, mm[n]);
      float contrib = tb * h;
      acc[jj] += (htid < ksg[jj]) ? contrib : 0.0f;  // select AFTER compute
    }
  }

  // ---- near field: masked sweep reading staged LDS (float4) ----
  for (int kb = lo_g + htid * 4; kb <= smax_g; kb += 256 * 4) {
    int idx = kb - ubase;  // multiple of 4 (both 256-aligned bases)
    float ce[4], de[4], ge[4];
    if (idx < LSTG) {
      float4 c4 = *(const float4*)&lc[idx];
      float4 d4 = *(const float4*)&ldd[idx];
      float4 g4 = *(const float4*)&lgp[idx];
      ce[0]=c4.x; ce[1]=c4.y; ce[2]=c4.z; ce[3]=c4.w;
      de[0]=d4.x; de[1]=d4.y; de[2]=d4.z; de[3]=d4.w;
      ge[0]=g4.x; ge[1]=g4.y; ge[2]=g4.z; ge[3]=g4.w;
    } else {  // rare fallback: span exceeded LSTG
#pragma unroll
      for (int e = 0; e < 4; ++e) {
        int k = kb + e;
        if (k < 1 || k >= T) { ce[e]=0.0f; de[e]=1.0f; ge[e]=0.0f; }
        else {
          float lg = __logf(lrs[k]);
          float c  = C * __expf(-gam * lg);
          ce[e] = c; de[e] = fmaf(-c, lr_sum[k - 1], 1.0f); ge[e] = lr_gap[k];
        }
      }
    }
#pragma unroll
    for (int e = 0; e < 4; ++e) {
#pragma unroll
      for (int jj = 0; jj < HSZ; ++jj) {
        float inner = fmaf(ce[e], Ss[jj], de[e]);  // may be <=0 if masked
        float p = USE_RSQ ? RSQF(inner) : __expf(nb * __logf(inner));
        unsigned off = (unsigned)(kb + e - (ksg[jj] << SEGSH));
        unsigned rngj = (unsigned)(sv[jj] - (ksg[jj] << SEGSH));
        float pm = (off <= rngj) ? p : 0.0f;  // select AFTER p (NaN-safe)
        acc[jj] = fmaf(ge[e], pm, acc[jj]);
      }
    }
  }

  // ---- block reduce ----
#pragma unroll
  for (int jj = 0; jj < HSZ; ++jj) {
    float v = acc[jj];
#pragma unroll
    for (int off = 32; off; off >>= 1) v += __shfl_down(v, off, 64);
    if (lane == 0) wacc[wid][jb + jj] = v;
  }
  __syncthreads();

  // ---- epilogue + tree-reduced deterministic global sum (R16, proven) ----
  long long ll = 0;
  if (tid < GSZ) {
    int j = tid;
    int m = mbase + j;
    int w0 = (j >> 3) * 4;
    float sgp = wacc[w0][j] + wacc[w0 + 1][j] + wacc[w0 + 2][j] + wacc[w0 + 3][j];
    int s = step[m];
    float Ssum = S1[m];
    float LD = (lrs[0] - lrs[s]) - sgp;   // telescoped gap sum
    float pred = L0_p[0] + A_p[0] * fast_pow(Ssum, -alpha_p[0]) + B_p[0] * LD;
    pred = fmaxf(pred, 1e-10f);
    float r = __logf(loss[m]) - __logf(pred);
    float a = fabsf(r);
    const float dlt = 0.001f;
    float hubv = (a <= dlt) ? (0.5f * r * r) : (dlt * (a - 0.5f * dlt));
    ll = (long long)(hubv * SCALEF + 0.5f);  // hubv >= 0
  }
  if (wid == 0) {
#pragma unroll
    for (int off = 16; off; off >>= 1) ll += __shfl_down(ll, off, 64);
    if (lane == 0) {
      int gi = bid / GRPBLK;
      __hip_atomic_fetch_add(&g_grp[gi].acc, ll, __ATOMIC_RELAXED,
                             __HIP_MEMORY_SCOPE_AGENT);
      unsigned old = __hip_atomic_fetch_add(&g_grp[gi].cnt, 1u,
                                            __ATOMIC_ACQ_REL,
                                            __HIP_MEMORY_SCOPE_AGENT);
      if (old == GRPBLK - 1) {
        long long gsum = __hip_atomic_load(&g_grp[gi].acc, __ATOMIC_RELAXED,
                                           __HIP_MEMORY_SCOPE_AGENT);
        __hip_atomic_store(&g_grp[gi].acc, 0ll, __ATOMIC_RELAXED,
                           __HIP_MEMORY_SCOPE_AGENT);
        __hip_atomic_store(&g_grp[gi].cnt, 0u, __ATOMIC_RELAXED,
                           __HIP_MEMORY_SCOPE_AGENT);
        __hip_atomic_fetch_add(&g_root.acc, gsum, __ATOMIC_RELAXED,
                               __HIP_MEMORY_SCOPE_AGENT);
        unsigned old2 = __hip_atomic_fetch_add(&g_root.cnt, 1u,
                                               __ATOMIC_ACQ_REL,
                                               __HIP_MEMORY_SCOPE_AGENT);
        if (old2 == (NBLK / GRPBLK) - 1) {
          long long tot = __hip_atomic_load(&g_root.acc, __ATOMIC_RELAXED,
                                            __HIP_MEMORY_SCOPE_AGENT);
          out[0] = (float)((double)tot * INV_SCALE);
          __hip_atomic_store(&g_root.acc, 0ll, __ATOMIC_RELAXED,
                             __HIP_MEMORY_SCOPE_AGENT);
          __hip_atomic_store(&g_root.cnt, 0u, __ATOMIC_RELAXED,
                             __HIP_MEMORY_SCOPE_AGENT);
        }
      }
    }
  }
}

__global__ __launch_bounds__(BLK) void fused_kernel(
    const float* __restrict__ S1, const int* __restrict__ step,
    const float* __restrict__ loss, const float* __restrict__ lrs,
    const float* __restrict__ lr_sum, const float* __restrict__ lr_gap,
    const float* __restrict__ L0_p, const float* __restrict__ A_p,
    const float* __restrict__ alpha_p, const float* __restrict__ B_p,
    const float* __restrict__ C_p, const float* __restrict__ beta_p,
    const float* __restrict__ gamma_p,
    float* __restrict__ out, int T) {
  __shared__ float segm[MAXSEG][LSTRIDE];
  __shared__ __align__(16) float lc[LSTG];
  __shared__ __align__(16) float ldd[LSTG];
  __shared__ __align__(16) float lgp[LSTG];
  __shared__ float wacc[NW][GSZ];

  float beta = beta_p[0];
  float C = C_p[0], gam = gamma_p[0];
  if (beta == 0.5f)
    body<true>(S1, step, loss, lrs, lr_sum, lr_gap, L0_p, A_p, alpha_p, B_p,
               C, -0.5f, out, T, segm, lc, ldd, lgp, wacc, gam);
  else
    body<false>(S1, step, loss, lrs, lr_sum, lr_gap, L0_p, A_p, alpha_p, B_p,
                C, -beta, out, T, segm, lc, ldd, lgp, wacc, gam);
}

extern "C" void kernel_launch(void* const* d_in, const int* in_sizes, int n_in,
                              void* d_out, int out_size, void* d_ws, size_t ws_size,
                              hipStream_t stream) {
  const float* S1      = (const float*)d_in[0];
  const float* lrs     = (const float*)d_in[1];
  const float* lr_sum  = (const float*)d_in[2];
  const int*   step    = (const int*)  d_in[3];
  const float* lr_gap  = (const float*)d_in[4];
  const float* loss    = (const float*)d_in[5];
  const float* L0_p    = (const float*)d_in[6];
  const float* A_p     = (const float*)d_in[7];
  const float* alpha_p = (const float*)d_in[8];
  const float* B_p     = (const float*)d_in[9];
  const float* C_p     = (const float*)d_in[10];
  const float* beta_p  = (const float*)d_in[11];
  const float* gamma_p = (const float*)d_in[12];

  int M = in_sizes[0];
  int T = in_sizes[1];

  fused_kernel<<<M / GSZ, BLK, 0, stream>>>(
      S1, step, loss, lrs, lr_sum, lr_gap,
      L0_p, A_p, alpha_p, B_p, C_p, beta_p, gamma_p,
      (float*)d_out, T);
}